// Round 3
// baseline (181.467 us; speedup 1.0000x reference)
//
#include <hip/hip_runtime.h>
#include <hip/hip_bf16.h>

typedef __attribute__((ext_vector_type(8))) short short8;
typedef __attribute__((ext_vector_type(4))) float f32x4;

// ws layout (bytes)
#define WFT_OFF 0          // bf16[256*512]          = 262144 B
#define HB_OFF  262144     // f32[32*256]            =  32768 B
#define SC_OFF  294912     // f32[131072] scores     = 524288 B
#define ST_OFF  819200     // f32[4096*2] m,l        =  32768 B
#define CP_OFF  851968     // f32[4096*512] ctx part = 8388608 B (total ~9.2 MB)

// LDS per block (33.4 KB -> 4 blocks/CU on 160 KB):
//   Ab    [32][512] bf16 swizzled @0     (32768 B)
//   wpart [4][32]   f32           @32768 (  512 B)
//   wbuf  [32]      f32           @33280 (  128 B)
#define SMEM_MAIN 33408

__device__ __forceinline__ float bf2f(unsigned short h) {
    unsigned u = ((unsigned)h) << 16;
    return __builtin_bit_cast(float, u);
}
// native cvt path: compiler emits v_cvt_pk_bf16_f32 (RTNE), ~3 inst vs ~10 for bit-trick
__device__ __forceinline__ unsigned pack_bf16(float a, float b) {
    unsigned short sa = __builtin_bit_cast(unsigned short, __float2bfloat16(a));
    unsigned short sb = __builtin_bit_cast(unsigned short, __float2bfloat16(b));
    return (unsigned)sa | ((unsigned)sb << 16);
}
__device__ __forceinline__ float fast_tanh(float x) {
    float e2 = __expf(2.0f * x);
    return 1.0f - 2.0f / (e2 + 1.0f);
}
// LDS-only barrier: no vmcnt drain (only LDS data crosses intra-block barriers).
__device__ __forceinline__ void lds_barrier() {
    asm volatile("s_waitcnt lgkmcnt(0)" ::: "memory");
    __builtin_amdgcn_s_barrier();
}

// ---- Wf (512x256 f32) -> WfT (256x512 bf16), tiled transpose ----
__global__ void wft_kernel(const float* __restrict__ Wf, unsigned short* __restrict__ WfT) {
    __shared__ unsigned short tl[64 * 80];
    const int t = threadIdx.x;
    const int tk = blockIdx.x >> 2, ta = blockIdx.x & 3;
    const int d0 = tk * 64, a0 = ta * 64;
#pragma unroll
    for (int i = 0; i < 16; ++i) {
        int flat = t + 256 * i;
        int dl = flat >> 6, al = flat & 63;
        tl[al * 80 + dl] = __builtin_bit_cast(unsigned short,
                               __float2bfloat16(Wf[(d0 + dl) * 256 + a0 + al]));
    }
    __syncthreads();
#pragma unroll
    for (int i = 0; i < 2; ++i) {
        int u = t + 256 * i;
        int al = u >> 3, q = u & 7;
        *(uint4*)(&WfT[(size_t)(a0 + al) * 512 + d0 + q * 8]) =
            *(const uint4*)(&tl[al * 80 + q * 8]);
    }
}

// ---- hb[b][a] = hidden[b]·Wh[:,a] + bh[a] + bf[a] ----
__global__ void hb_kernel(const float* __restrict__ hidden, const float* __restrict__ Wh,
                          const float* __restrict__ bh, const float* __restrict__ bfv,
                          float* __restrict__ hb) {
    const int b = blockIdx.x, a = threadIdx.x;
    float acc = bh[a] + bfv[a];
    const float* hrow = hidden + b * 512;
#pragma unroll 8
    for (int d = 0; d < 512; ++d)
        acc += hrow[d] * Wh[d * 256 + a];
    hb[b * 256 + a] = acc;
}

// ---- fused: 32-row tiles, 256 thr, 4 blocks/CU; B streamed from L2 ----
__launch_bounds__(256, 4)
__global__ void main_kernel(const float* __restrict__ feats,
                            const unsigned short* __restrict__ WfT,
                            const float* __restrict__ hbg,
                            const float* __restrict__ Ws,
                            float* __restrict__ scores,
                            float* __restrict__ stats,
                            float* __restrict__ ctxp) {
    extern __shared__ char smem[];
    char* Ab     = smem;                        // [32][1024 B] bf16, XOR-swizzled rows
    float* wpart = (float*)(smem + 32768);      // [4][32]
    float* wbuf  = (float*)(smem + 33280);      // [32]

    const int t = threadIdx.x;
    const int tile = blockIdx.x;
    const int b = tile >> 7;                    // 128 tiles per batch
    const int row0 = tile * 32;
    const int lane = t & 63, w = t >> 6;        // 4 waves; wave w owns cols w*64..w*64+63
    const int lr = lane & 15, lg = lane >> 4;
    const int sw = (lr & 7) << 4;

    // ---- stage A tile: feats f32 -> bf16 LDS (flat-contiguous loads) ----
    {
        const float4* fp = (const float4*)feats + (size_t)row0 * 128;
        const int col4 = t & 127;               // constant per thread
        const int r0 = t >> 7;                  // 0 or 1
#pragma unroll
        for (int i = 0; i < 16; ++i) {
            int row = r0 + i * 2;
            float4 v = fp[(size_t)t + i * 256];
            uint2 u;
            u.x = pack_bf16(v.x, v.y);
            u.y = pack_bf16(v.z, v.w);
            *(uint2*)(Ab + row * 1024 + ((col4 * 8) ^ ((row & 7) << 4))) = u;
        }
    }

    // epilogue operands straight from global (L2-hit)
    float hbv[4], wsv[4];
#pragma unroll
    for (int j = 0; j < 4; ++j) {
        int col = w * 64 + j * 16 + lr;
        hbv[j] = hbg[b * 256 + col];
        wsv[j] = Ws[col];
    }

    lds_barrier();                              // A tile staged

    // ---- GEMM 32x256x512: wave w -> 32 rows x 64 cols, K chunks of 32 ----
    f32x4 acc[2][4] = {};
    const unsigned short* bp[4];
#pragma unroll
    for (int j = 0; j < 4; ++j)
        bp[j] = WfT + (size_t)(w * 64 + j * 16 + lr) * 512 + lg * 8;

    uint4 bfr[2][4];                            // [buf][j], static under unroll
#pragma unroll
    for (int j = 0; j < 4; ++j) bfr[0][j] = *(const uint4*)(bp[j]);

#pragma unroll
    for (int ks = 0; ks < 16; ++ks) {
        const int cur = ks & 1, nxt = cur ^ 1;
        if (ks < 15) {                          // 1-deep B prefetch from L2
#pragma unroll
            for (int j = 0; j < 4; ++j)
                bfr[nxt][j] = *(const uint4*)(bp[j] + (ks + 1) * 32);
        }
        short8 af[2];
#pragma unroll
        for (int i = 0; i < 2; ++i) {
            int row = i * 16 + lr;
            af[i] = *(const short8*)(Ab + row * 1024 + ((ks * 64 + lg * 16) ^ sw));
        }
#pragma unroll
        for (int i = 0; i < 2; ++i)
#pragma unroll
            for (int j = 0; j < 4; ++j)
                acc[i][j] = __builtin_amdgcn_mfma_f32_16x16x32_bf16(
                    af[i], __builtin_bit_cast(short8, bfr[cur][j]), acc[i][j], 0, 0, 0);
    }

    // ---- epilogue: scores = sum_a tanh(C + hb[a]) * Ws[a] ----
#pragma unroll
    for (int i = 0; i < 2; ++i) {
#pragma unroll
        for (int r = 0; r < 4; ++r) {
            float p = 0.f;
#pragma unroll
            for (int j = 0; j < 4; ++j)
                p += fast_tanh(acc[i][j][r] + hbv[j]) * wsv[j];
#pragma unroll
            for (int off = 1; off < 16; off <<= 1) p += __shfl_xor(p, off, 64);
            if (lr == 0) wpart[w * 32 + i * 16 + lg * 4 + r] = p;
        }
    }
    lds_barrier();

    // block softmax stats (first 32 lanes)
    if (t < 32) {
        float s = wpart[t] + wpart[32 + t] + wpart[64 + t] + wpart[96 + t];
        scores[row0 + t] = s;
        float m = s;
#pragma unroll
        for (int off = 1; off < 32; off <<= 1) m = fmaxf(m, __shfl_xor(m, off, 32));
        float e = __expf(s - m);
        float l = e;
#pragma unroll
        for (int off = 1; off < 32; off <<= 1) l += __shfl_xor(l, off, 32);
        wbuf[t] = e;
        if (t == 0) { stats[tile * 2] = m; stats[tile * 2 + 1] = l; }
    }
    lds_barrier();

    // ---- ctx partial: thread t owns d-cols {2t, 2t+1}, no scratch needed ----
    {
        float c0 = 0.f, c1 = 0.f;
        const int byt = t * 4;                  // byte offset of d-pair within row
#pragma unroll 8
        for (int n = 0; n < 32; ++n) {
            float wv = wbuf[n];
            unsigned a2 = *(const unsigned*)(Ab + n * 1024 + (byt ^ ((n & 7) << 4)));
            c0 += wv * bf2f((unsigned short)a2);
            c1 += wv * bf2f((unsigned short)(a2 >> 16));
        }
        float2 v; v.x = c0; v.y = c1;
        *(float2*)(ctxp + (size_t)tile * 512 + t * 2) = v;
    }
}

// ---- per-batch: global softmax (128 partials) + alpha + ctx merge ----
__global__ void combine_kernel(const float* __restrict__ scores,
                               const float* __restrict__ stats,
                               const float* __restrict__ ctxp,
                               float* __restrict__ out_ctx,
                               float* __restrict__ out_alpha) {
    __shared__ float scales[128];
    __shared__ float red[4];
    const int b = blockIdx.x, t = threadIdx.x;
    float mk = -1e30f, lk = 0.f, e = 0.f;
    if (t < 128) {
        mk = stats[(b * 128 + t) * 2];
        lk = stats[(b * 128 + t) * 2 + 1];
    }
    float M = mk;
#pragma unroll
    for (int off = 1; off < 64; off <<= 1) M = fmaxf(M, __shfl_xor(M, off, 64));
    if ((t & 63) == 0) red[t >> 6] = M;
    __syncthreads();
    M = fmaxf(red[0], red[1]);
    if (t < 128) e = __expf(mk - M);
    float z = e * lk;
#pragma unroll
    for (int off = 1; off < 64; off <<= 1) z += __shfl_xor(z, off, 64);
    __syncthreads();                            // red[] reuse
    if ((t & 63) == 0) red[t >> 6] = z;
    __syncthreads();
    const float Z = red[0] + red[1];
    if (t < 128) scales[t] = e / Z;
    __syncthreads();

    const float invZ = 1.0f / Z;
    const float* sb = scores + b * 4096;
    float* abp = out_alpha + b * 4096;
#pragma unroll
    for (int i = 0; i < 16; ++i) {
        int n = t + 256 * i;
        abp[n] = __expf(sb[n] - M) * invZ;
    }
    const int d0 = t * 2;
    float2 acc; acc.x = 0.f; acc.y = 0.f;
    for (int k = 0; k < 128; ++k) {
        float sc = scales[k];
        const float2 v = *(const float2*)(ctxp + ((size_t)(b * 128 + k) * 512 + d0));
        acc.x += sc * v.x; acc.y += sc * v.y;
    }
    *(float2*)(out_ctx + b * 512 + d0) = acc;
}

extern "C" void kernel_launch(void* const* d_in, const int* in_sizes, int n_in,
                              void* d_out, int out_size, void* d_ws, size_t ws_size,
                              hipStream_t stream) {
    (void)in_sizes; (void)n_in; (void)out_size; (void)ws_size;
    const float* feats  = (const float*)d_in[0];
    const float* hidden = (const float*)d_in[1];
    const float* Wf     = (const float*)d_in[2];
    const float* bfv    = (const float*)d_in[3];
    const float* Wh     = (const float*)d_in[4];
    const float* bh     = (const float*)d_in[5];
    const float* Ws     = (const float*)d_in[6];
    // d_in[7] (bs) irrelevant: softmax is shift-invariant and scores are not output.

    char* ws = (char*)d_ws;
    unsigned short* WfT = (unsigned short*)(ws + WFT_OFF);
    float* hb     = (float*)(ws + HB_OFF);
    float* scores = (float*)(ws + SC_OFF);
    float* stats  = (float*)(ws + ST_OFF);
    float* ctxp   = (float*)(ws + CP_OFF);

    float* out_ctx   = (float*)d_out;
    float* out_alpha = out_ctx + 32 * 512;

    hipFuncSetAttribute((const void*)main_kernel,
                        hipFuncAttributeMaxDynamicSharedMemorySize, SMEM_MAIN);

    hipLaunchKernelGGL(wft_kernel, dim3(32), dim3(256), 0, stream, Wf, WfT);
    hipLaunchKernelGGL(hb_kernel, dim3(32), dim3(256), 0, stream, hidden, Wh, bh, bfv, hb);
    hipLaunchKernelGGL(main_kernel, dim3(4096), dim3(256), SMEM_MAIN, stream,
                       feats, WfT, hb, Ws, scores, stats, ctxp);
    hipLaunchKernelGGL(combine_kernel, dim3(32), dim3(256), 0, stream,
                       scores, stats, ctxp, out_ctx, out_alpha);
}